// Round 9
// baseline (347.417 us; speedup 1.0000x reference)
//
#include <hip/hip_runtime.h>

// Round 9: round-8 structure + (a) register-staged aggS chunks (no bkt re-read),
// (b) k_part bucket-id side-stage instead of binary search, (c) 4x parallelism
// in gemm1/hist, (d) memset folded into k_detect. Assumes Nn <= 131072.

// ---------- bf16 helpers ----------
__device__ __forceinline__ float bf2f(unsigned int u16) {
    return __uint_as_float(u16 << 16);
}
__device__ __forceinline__ unsigned short f2bf(float f) {
    unsigned int u = __float_as_uint(f);
    u += 0x7fffu + ((u >> 16) & 1u);
    return (unsigned short)(u >> 16);
}

__device__ __forceinline__ void atomAddF(float* p, float v) {
    unsafeAtomicAdd(p, v);  // global_atomic_add_f32
}

// ---------------- kernel: runtime encoding detection + zero hist ----------------
__global__ __launch_bounds__(256) void k_detect(const unsigned int* __restrict__ xw,
                                                const unsigned int* __restrict__ eiw,
                                                int* __restrict__ flags,
                                                int* __restrict__ hist) {
    __shared__ int votes[2];
    int tid = threadIdx.x;
    hist[tid] = 0; hist[tid + 256] = 0;
    if (tid == 0) { votes[0] = 0; votes[1] = 0; }
    __syncthreads();
    unsigned int w = xw[tid];
    unsigned int lo = w & 0xffffu;
    unsigned int elo = (lo >> 7) & 0xffu;
    int bfvote = (lo == 0u || (elo >= 100u && elo <= 140u)) ? 1 : 0;
    int nzvote = (eiw[2 * tid + 1] != 0u) ? 1 : 0;
    atomicAdd(&votes[0], bfvote);
    atomicAdd(&votes[1], nzvote);
    __syncthreads();
    if (tid == 0) {
        flags[0] = (votes[0] >= 160) ? 1 : 0;
        flags[1] = (votes[1] == 0) ? 1 : 0;
    }
}

// ---------------- kernel: bucket histogram (bucket = dst>>8), 2048 edges/block ----------------
__global__ __launch_bounds__(256) void k_hist(const int* __restrict__ ei,
                                              const int* __restrict__ flags,
                                              int* __restrict__ hist, int E, int Nn) {
    __shared__ int lh[512];
    int tid = threadIdx.x;
    lh[tid] = 0; lh[tid + 256] = 0;
    __syncthreads();
    int is64 = flags[1];
    int e0 = blockIdx.x * 2048;
    #pragma unroll
    for (int i = 0; i < 8; ++i) {
        int e = e0 + i * 256 + tid;
        if (e < E) {
            int d = is64 ? ei[2 * (E + e)] : ei[E + e];
            if ((unsigned)d < (unsigned)Nn) atomicAdd(&lh[d >> 8], 1);
        }
    }
    __syncthreads();
    int NB = (Nn + 255) >> 8;
    for (int b = tid; b < NB; b += 256) {
        int c = lh[b];
        if (c) atomicAdd(&hist[b], c);
    }
}

// ---------------- kernel: scan hist -> base[0..NB], cursor ----------------
__global__ __launch_bounds__(512) void k_scanB(const int* __restrict__ hist,
                                               int* __restrict__ base,
                                               int* __restrict__ cursor, int NB) {
    __shared__ int sa[512], sb[512];
    int tid = threadIdx.x;
    int v = (tid < NB) ? hist[tid] : 0;
    sa[tid] = v;
    __syncthreads();
    int* cur = sa; int* nxt = sb;
    for (int off = 1; off < 512; off <<= 1) {
        nxt[tid] = cur[tid] + ((tid >= off) ? cur[tid - off] : 0);
        __syncthreads();
        int* t = cur; cur = nxt; nxt = t;
    }
    int excl = cur[tid] - v;
    if (tid < NB) { base[tid] = excl; cursor[tid] = excl; }
    if (tid == NB - 1) base[NB] = excl + v;
}

// ---------------- kernel: partition edges into dst-buckets ----------------
// packed entry: s (17 bits) | (d&255) << 17
#define PCHUNK 4096
__global__ __launch_bounds__(256) void k_part(const int* __restrict__ ei,
                                              const int* __restrict__ flags,
                                              int* __restrict__ cursor,
                                              unsigned int* __restrict__ bkt,
                                              int E, int Nn) {
    __shared__ int lhist[512];
    __shared__ int lexcl[512];
    __shared__ int lbase[512];
    __shared__ int sa[512], sb[512];
    __shared__ unsigned int stage[PCHUNK];   // 16 KB
    __shared__ ushort sbk[PCHUNK];           // 8 KB: bucket id per staged slot
    __shared__ int stot_s;
    int tid = threadIdx.x;
    lhist[tid] = 0; lhist[tid + 256] = 0;
    __syncthreads();
    int is64 = flags[1];
    int e0 = blockIdx.x * PCHUNK;
    int ss[16], dd[16];
    #pragma unroll
    for (int i = 0; i < 16; ++i) {
        int e = e0 + i * 256 + tid;
        int s = -1, d = -1;
        if (e < E) {
            if (is64) { s = ei[2 * e]; d = ei[2 * (E + e)]; }
            else      { s = ei[e];     d = ei[E + e]; }
            if ((unsigned)s >= (unsigned)Nn || (unsigned)d >= (unsigned)Nn) { s = -1; d = -1; }
        }
        ss[i] = s; dd[i] = d;
        if (d >= 0) atomicAdd(&lhist[d >> 8], 1);
    }
    __syncthreads();
    sa[tid] = lhist[tid]; sa[tid + 256] = lhist[tid + 256];
    __syncthreads();
    int* cur = sa; int* nxt = sb;
    for (int off = 1; off < 512; off <<= 1) {
        nxt[tid] = cur[tid] + ((tid >= off) ? cur[tid - off] : 0);
        int t2 = tid + 256;
        nxt[t2] = cur[t2] + ((t2 >= off) ? cur[t2 - off] : 0);
        __syncthreads();
        int* t = cur; cur = nxt; nxt = t;
    }
    lexcl[tid] = cur[tid] - lhist[tid];
    lexcl[tid + 256] = cur[tid + 256] - lhist[tid + 256];
    if (tid == 0) stot_s = cur[511];
    __syncthreads();
    for (int b = tid; b < 512; b += 256) {
        int c = lhist[b];
        lbase[b] = c ? atomicAdd(&cursor[b], c) : 0;
        lhist[b] = lexcl[b];   // running cursor
    }
    __syncthreads();
    #pragma unroll
    for (int i = 0; i < 16; ++i) {
        if (dd[i] >= 0) {
            int b = dd[i] >> 8;
            int q = atomicAdd(&lhist[b], 1);
            stage[q] = (unsigned)ss[i] | ((unsigned)(dd[i] & 255) << 17);
            sbk[q] = (ushort)b;
        }
    }
    __syncthreads();
    int stot = stot_s;
    for (int q = tid; q < stot; q += 256) {
        int b = sbk[q];
        bkt[lbase[b] + (q - lexcl[b])] = stage[q];
    }
}

// ---------------- kernel: per-bucket degree -> dinv ----------------
__global__ __launch_bounds__(256) void k_dinv(const unsigned int* __restrict__ bkt,
                                              const int* __restrict__ base,
                                              float* __restrict__ dinv, int Nn) {
    __shared__ int ldeg[256];
    int tid = threadIdx.x, b = blockIdx.x;
    ldeg[tid] = 0;
    __syncthreads();
    int st = base[b], en = base[b + 1];
    for (int e = st + tid; e < en; e += 256) {
        unsigned p = bkt[e];
        atomicAdd(&ldeg[(p >> 17) & 255], 1);
    }
    __syncthreads();
    int n = b * 256 + tid;
    if (n < Nn) dinv[n] = rsqrtf((float)(ldeg[tid] + 1));  // +1 self loop
}

// ---------------- kernel: hs = (x @ W1) * dinv ; agg init = hs ; 64 nodes/block ----------------
__global__ __launch_bounds__(256) void k_gemm1(const void* __restrict__ xraw,
                                               const void* __restrict__ w1raw,
                                               const int* __restrict__ flags,
                                               const float* __restrict__ dinv,
                                               float* __restrict__ hs,
                                               float* __restrict__ agg, int Nn) {
    __shared__ float sWt[16 * 132];
    const int isbf = flags[0];
    const ushort* xb = (const ushort*)xraw;
    const float* xf = (const float*)xraw;
    int tid = threadIdx.x;
    if (isbf) {
        const ushort* w1 = (const ushort*)w1raw;
        for (int i = tid; i < 2048; i += 256) {
            int k = i >> 4, j = i & 15;
            sWt[j * 132 + k] = bf2f(w1[i]);
        }
    } else {
        const float* w1 = (const float*)w1raw;
        for (int i = tid; i < 2048; i += 256) {
            int k = i >> 4, j = i & 15;
            sWt[j * 132 + k] = w1[i];
        }
    }
    __syncthreads();
    int hq = tid & 3;
    int n = blockIdx.x * 64 + (tid >> 2);
    float acc[4] = {0.f, 0.f, 0.f, 0.f};
    if (n < Nn) {
        for (int ko = 0; ko < 16; ++ko) {
            float xv[8];
            if (isbf) {
                uint4 q = *reinterpret_cast<const uint4*>(xb + (size_t)n * 128 + ko * 8);
                xv[0] = bf2f(q.x & 0xffffu); xv[1] = bf2f(q.x >> 16);
                xv[2] = bf2f(q.y & 0xffffu); xv[3] = bf2f(q.y >> 16);
                xv[4] = bf2f(q.z & 0xffffu); xv[5] = bf2f(q.z >> 16);
                xv[6] = bf2f(q.w & 0xffffu); xv[7] = bf2f(q.w >> 16);
            } else {
                const float4* p = reinterpret_cast<const float4*>(xf + (size_t)n * 128 + ko * 8);
                float4 a = p[0], bb = p[1];
                xv[0] = a.x; xv[1] = a.y; xv[2] = a.z; xv[3] = a.w;
                xv[4] = bb.x; xv[5] = bb.y; xv[6] = bb.z; xv[7] = bb.w;
            }
            #pragma unroll
            for (int c = 0; c < 4; ++c) {
                const float* wr = &sWt[(hq * 4 + c) * 132 + ko * 8];
                float4 w0 = *reinterpret_cast<const float4*>(wr);
                float4 w1v = *reinterpret_cast<const float4*>(wr + 4);
                acc[c] += xv[0] * w0.x + xv[1] * w0.y + xv[2] * w0.z + xv[3] * w0.w
                        + xv[4] * w1v.x + xv[5] * w1v.y + xv[6] * w1v.z + xv[7] * w1v.w;
            }
        }
        float dv = dinv[n];
        float4 o = make_float4(acc[0] * dv, acc[1] * dv, acc[2] * dv, acc[3] * dv);
        *reinterpret_cast<float4*>(hs + (size_t)n * 16 + hq * 4) = o;
        *reinterpret_cast<float4*>(agg + (size_t)n * 16 + hq * 4) = o;  // self-loop init
    }
}

// ---------------- kernel: split bucket agg — register-staged counting-sort + runs ----------------
#define SPLITS 4
#define ACH 2048
__global__ __launch_bounds__(256) void k_aggS(const unsigned int* __restrict__ bkt,
                                              const int* __restrict__ base,
                                              const float* __restrict__ hs,
                                              float* __restrict__ agg, int Nn) {
    __shared__ float sAgg[4096];          // 16 KB
    __shared__ unsigned int sSorted[ACH]; // 8 KB
    __shared__ int cnt[256], excl[256];
    __shared__ int sc[2][256];
    __shared__ int tot_s;
    int tid = threadIdx.x;
    int b = blockIdx.x >> 2, sp = blockIdx.x & 3;
    for (int i = tid; i < 4096; i += 256) sAgg[i] = 0.f;
    int st = base[b], en = base[b + 1];
    int len = en - st;
    int s0 = st + (int)(((long long)len * sp) >> 2);
    int s1 = st + (int)(((long long)len * (sp + 1)) >> 2);
    int g = tid >> 4, j = tid & 15;
    for (int c0 = s0; c0 < s1; c0 += ACH) {
        cnt[tid] = 0;
        __syncthreads();
        // register-stage up to 8 entries/thread; histogram by node-in-bucket
        unsigned ue[8];
        #pragma unroll
        for (int i = 0; i < 8; ++i) {
            int idx = c0 + i * 256 + tid;
            if (idx < s1) {
                ue[i] = bkt[idx];
                atomicAdd(&cnt[(ue[i] >> 17) & 255u], 1);
            } else ue[i] = 0xffffffffu;
        }
        __syncthreads();
        // 256-wide scan of cnt
        int v = cnt[tid];
        sc[0][tid] = v;
        __syncthreads();
        int pi = 0;
        for (int off = 1; off < 256; off <<= 1) {
            sc[pi ^ 1][tid] = sc[pi][tid] + ((tid >= off) ? sc[pi][tid - off] : 0);
            __syncthreads();
            pi ^= 1;
        }
        int ex = sc[pi][tid] - v;
        excl[tid] = ex;
        cnt[tid] = ex;   // becomes running cursor
        if (tid == 255) tot_s = sc[pi][255];
        __syncthreads();
        // scatter from registers into sorted LDS order
        #pragma unroll
        for (int i = 0; i < 8; ++i) {
            if (ue[i] != 0xffffffffu) {
                int q = atomicAdd(&cnt[(ue[i] >> 17) & 255u], 1);
                sSorted[q] = ue[i];
            }
        }
        __syncthreads();
        // register-run accumulation: group g owns nodes [g*16, g*16+16)
        int segS = excl[g * 16];
        int segE = (g == 15) ? tot_s : excl[g * 16 + 16];
        float acc = 0.f; int curn = -1;
        for (int k = segS; k < segE; k += 8) {
            int m = segE - k;
            unsigned e[8]; float vv[8];
            #pragma unroll
            for (int i = 0; i < 8; ++i) e[i] = (i < m) ? sSorted[k + i] : 0xffffffffu;
            #pragma unroll
            for (int i = 0; i < 8; ++i)
                vv[i] = (e[i] != 0xffffffffu) ? hs[(size_t)(e[i] & 0x1ffffu) * 16 + j] : 0.f;
            #pragma unroll
            for (int i = 0; i < 8; ++i) {
                if (e[i] != 0xffffffffu) {
                    int nn = (int)((e[i] >> 17) & 255u);
                    if (nn != curn) { if (curn >= 0) sAgg[curn * 16 + j] += acc; acc = 0.f; curn = nn; }
                    acc += vv[i];
                }
            }
        }
        if (curn >= 0) sAgg[curn * 16 + j] += acc;
        __syncthreads();
    }
    // coalesced zero-skip combine into global agg
    int nbase = b << 8;
    for (int i = tid; i < 4096; i += 256) {
        int n = nbase + (i >> 4);
        float v = sAgg[i];
        bool nz = (n < Nn) && (v != 0.f);
        if (__any(nz)) {
            if (n < Nn) atomAddF(&agg[(size_t)n * 16 + (i & 15)], v);
        }
    }
}

// ---------------- kernel: *dinv + bias + relu -> @Wp+bp -> softmax -> out ----------------
__global__ __launch_bounds__(256) void k_final(const float* __restrict__ agg,
                                               const float* __restrict__ dinv,
                                               const void* __restrict__ b1raw,
                                               const void* __restrict__ wpraw,
                                               const void* __restrict__ bpraw,
                                               const int* __restrict__ flags,
                                               void* __restrict__ outraw, int Nn) {
    __shared__ float sWp[256];
    __shared__ float sA[256];
    const int isbf = flags[0];
    int tid = threadIdx.x;
    sWp[tid] = isbf ? bf2f(((const ushort*)wpraw)[tid]) : ((const float*)wpraw)[tid];
    int n0 = blockIdx.x * 16;
    int nl = tid >> 4, c = tid & 15;
    int n = n0 + nl;
    float b1v = isbf ? bf2f(((const ushort*)b1raw)[c]) : ((const float*)b1raw)[c];
    float bpv = isbf ? bf2f(((const ushort*)bpraw)[c]) : ((const float*)bpraw)[c];
    float av = (n < Nn) ? agg[(size_t)n * 16 + c] * dinv[n] : 0.f;
    sA[tid] = fmaxf(av + b1v, 0.f);
    __syncthreads();
    float acc = bpv;
    #pragma unroll
    for (int jj = 0; jj < 16; ++jj) acc += sA[nl * 16 + jj] * sWp[jj * 16 + c];
    float m = acc;
    #pragma unroll
    for (int off = 1; off < 16; off <<= 1) m = fmaxf(m, __shfl_xor(m, off, 16));
    float ev = __expf(acc - m);
    float s = ev;
    #pragma unroll
    for (int off = 1; off < 16; off <<= 1) s += __shfl_xor(s, off, 16);
    if (n < Nn) {
        float v = ev / s;
        if (isbf) ((ushort*)outraw)[(size_t)n * 16 + c] = f2bf(v);
        else      ((float*)outraw)[(size_t)n * 16 + c] = v;
    }
}

extern "C" void kernel_launch(void* const* d_in, const int* in_sizes, int n_in,
                              void* d_out, int out_size, void* d_ws, size_t ws_size,
                              hipStream_t stream) {
    const void* x  = d_in[0];
    const void* W1 = d_in[1];
    const void* b1 = d_in[2];
    const void* Wp = d_in[3];
    const void* bp = d_in[4];
    const int*  ei = (const int*)d_in[5];

    int Nn = in_sizes[0] / 128;
    int E  = in_sizes[5] / 2;
    int NB = (Nn + 255) >> 8;

    size_t Ns = (size_t)Nn;
    char* ws = (char*)d_ws;
    size_t off = 0;
    auto alloc = [&](size_t bytes) { void* p = ws + off; off += (bytes + 63) & ~(size_t)63; return p; };
    int*          flags  = (int*)alloc(64);
    float*        hs     = (float*)alloc(Ns * 16 * 4);
    float*        agg    = (float*)alloc(Ns * 16 * 4);
    float*        dinv   = (float*)alloc(Ns * 4);
    int*          hist   = (int*)alloc(512 * 4);
    int*          basep  = (int*)alloc(513 * 4);
    int*          cursor = (int*)alloc(512 * 4);
    unsigned int* bkt    = (unsigned int*)alloc((size_t)E * 4);

    k_detect<<<1, 256, 0, stream>>>((const unsigned int*)x, (const unsigned int*)ei, flags, hist);
    k_hist<<<(E + 2047) / 2048, 256, 0, stream>>>(ei, flags, hist, E, Nn);
    k_scanB<<<1, 512, 0, stream>>>(hist, basep, cursor, NB);
    k_part<<<(E + PCHUNK - 1) / PCHUNK, 256, 0, stream>>>(ei, flags, cursor, bkt, E, Nn);
    k_dinv<<<NB, 256, 0, stream>>>(bkt, basep, dinv, Nn);
    k_gemm1<<<(Nn + 63) / 64, 256, 0, stream>>>(x, W1, flags, dinv, hs, agg, Nn);
    k_aggS<<<NB * SPLITS, 256, 0, stream>>>(bkt, basep, hs, agg, Nn);
    k_final<<<(Nn + 15) / 16, 256, 0, stream>>>(agg, dinv, b1, Wp, bp, flags, d_out, Nn);
}

// Round 10
// 292.566 us; speedup vs baseline: 1.1875x; 1.1875x over previous
//
#include <hip/hip_runtime.h>

// Round 10: round-9 pipeline with k_gemm1 reverted to the round-8 (non-spilling)
// form. Assumes Nn <= 131072 (17-bit node ids).

// ---------- bf16 helpers ----------
__device__ __forceinline__ float bf2f(unsigned int u16) {
    return __uint_as_float(u16 << 16);
}
__device__ __forceinline__ unsigned short f2bf(float f) {
    unsigned int u = __float_as_uint(f);
    u += 0x7fffu + ((u >> 16) & 1u);
    return (unsigned short)(u >> 16);
}

__device__ __forceinline__ void atomAddF(float* p, float v) {
    unsafeAtomicAdd(p, v);  // global_atomic_add_f32
}

// ---------------- kernel: runtime encoding detection + zero hist ----------------
__global__ __launch_bounds__(256) void k_detect(const unsigned int* __restrict__ xw,
                                                const unsigned int* __restrict__ eiw,
                                                int* __restrict__ flags,
                                                int* __restrict__ hist) {
    __shared__ int votes[2];
    int tid = threadIdx.x;
    hist[tid] = 0; hist[tid + 256] = 0;
    if (tid == 0) { votes[0] = 0; votes[1] = 0; }
    __syncthreads();
    unsigned int w = xw[tid];
    unsigned int lo = w & 0xffffu;
    unsigned int elo = (lo >> 7) & 0xffu;
    int bfvote = (lo == 0u || (elo >= 100u && elo <= 140u)) ? 1 : 0;
    int nzvote = (eiw[2 * tid + 1] != 0u) ? 1 : 0;
    atomicAdd(&votes[0], bfvote);
    atomicAdd(&votes[1], nzvote);
    __syncthreads();
    if (tid == 0) {
        flags[0] = (votes[0] >= 160) ? 1 : 0;
        flags[1] = (votes[1] == 0) ? 1 : 0;
    }
}

// ---------------- kernel: bucket histogram (bucket = dst>>8), 2048 edges/block ----------------
__global__ __launch_bounds__(256) void k_hist(const int* __restrict__ ei,
                                              const int* __restrict__ flags,
                                              int* __restrict__ hist, int E, int Nn) {
    __shared__ int lh[512];
    int tid = threadIdx.x;
    lh[tid] = 0; lh[tid + 256] = 0;
    __syncthreads();
    int is64 = flags[1];
    int e0 = blockIdx.x * 2048;
    #pragma unroll
    for (int i = 0; i < 8; ++i) {
        int e = e0 + i * 256 + tid;
        if (e < E) {
            int d = is64 ? ei[2 * (E + e)] : ei[E + e];
            if ((unsigned)d < (unsigned)Nn) atomicAdd(&lh[d >> 8], 1);
        }
    }
    __syncthreads();
    int NB = (Nn + 255) >> 8;
    for (int b = tid; b < NB; b += 256) {
        int c = lh[b];
        if (c) atomicAdd(&hist[b], c);
    }
}

// ---------------- kernel: scan hist -> base[0..NB], cursor ----------------
__global__ __launch_bounds__(512) void k_scanB(const int* __restrict__ hist,
                                               int* __restrict__ base,
                                               int* __restrict__ cursor, int NB) {
    __shared__ int sa[512], sb[512];
    int tid = threadIdx.x;
    int v = (tid < NB) ? hist[tid] : 0;
    sa[tid] = v;
    __syncthreads();
    int* cur = sa; int* nxt = sb;
    for (int off = 1; off < 512; off <<= 1) {
        nxt[tid] = cur[tid] + ((tid >= off) ? cur[tid - off] : 0);
        __syncthreads();
        int* t = cur; cur = nxt; nxt = t;
    }
    int excl = cur[tid] - v;
    if (tid < NB) { base[tid] = excl; cursor[tid] = excl; }
    if (tid == NB - 1) base[NB] = excl + v;
}

// ---------------- kernel: partition edges into dst-buckets ----------------
// packed entry: s (17 bits) | (d&255) << 17
#define PCHUNK 4096
__global__ __launch_bounds__(256) void k_part(const int* __restrict__ ei,
                                              const int* __restrict__ flags,
                                              int* __restrict__ cursor,
                                              unsigned int* __restrict__ bkt,
                                              int E, int Nn) {
    __shared__ int lhist[512];
    __shared__ int lexcl[512];
    __shared__ int lbase[512];
    __shared__ int sa[512], sb[512];
    __shared__ unsigned int stage[PCHUNK];   // 16 KB
    __shared__ ushort sbk[PCHUNK];           // 8 KB: bucket id per staged slot
    __shared__ int stot_s;
    int tid = threadIdx.x;
    lhist[tid] = 0; lhist[tid + 256] = 0;
    __syncthreads();
    int is64 = flags[1];
    int e0 = blockIdx.x * PCHUNK;
    int ss[16], dd[16];
    #pragma unroll
    for (int i = 0; i < 16; ++i) {
        int e = e0 + i * 256 + tid;
        int s = -1, d = -1;
        if (e < E) {
            if (is64) { s = ei[2 * e]; d = ei[2 * (E + e)]; }
            else      { s = ei[e];     d = ei[E + e]; }
            if ((unsigned)s >= (unsigned)Nn || (unsigned)d >= (unsigned)Nn) { s = -1; d = -1; }
        }
        ss[i] = s; dd[i] = d;
        if (d >= 0) atomicAdd(&lhist[d >> 8], 1);
    }
    __syncthreads();
    sa[tid] = lhist[tid]; sa[tid + 256] = lhist[tid + 256];
    __syncthreads();
    int* cur = sa; int* nxt = sb;
    for (int off = 1; off < 512; off <<= 1) {
        nxt[tid] = cur[tid] + ((tid >= off) ? cur[tid - off] : 0);
        int t2 = tid + 256;
        nxt[t2] = cur[t2] + ((t2 >= off) ? cur[t2 - off] : 0);
        __syncthreads();
        int* t = cur; cur = nxt; nxt = t;
    }
    lexcl[tid] = cur[tid] - lhist[tid];
    lexcl[tid + 256] = cur[tid + 256] - lhist[tid + 256];
    if (tid == 0) stot_s = cur[511];
    __syncthreads();
    for (int b = tid; b < 512; b += 256) {
        int c = lhist[b];
        lbase[b] = c ? atomicAdd(&cursor[b], c) : 0;
        lhist[b] = lexcl[b];   // running cursor
    }
    __syncthreads();
    #pragma unroll
    for (int i = 0; i < 16; ++i) {
        if (dd[i] >= 0) {
            int b = dd[i] >> 8;
            int q = atomicAdd(&lhist[b], 1);
            stage[q] = (unsigned)ss[i] | ((unsigned)(dd[i] & 255) << 17);
            sbk[q] = (ushort)b;
        }
    }
    __syncthreads();
    int stot = stot_s;
    for (int q = tid; q < stot; q += 256) {
        int b = sbk[q];
        bkt[lbase[b] + (q - lexcl[b])] = stage[q];
    }
}

// ---------------- kernel: per-bucket degree -> dinv ----------------
__global__ __launch_bounds__(256) void k_dinv(const unsigned int* __restrict__ bkt,
                                              const int* __restrict__ base,
                                              float* __restrict__ dinv, int Nn) {
    __shared__ int ldeg[256];
    int tid = threadIdx.x, b = blockIdx.x;
    ldeg[tid] = 0;
    __syncthreads();
    int st = base[b], en = base[b + 1];
    for (int e = st + tid; e < en; e += 256) {
        unsigned p = bkt[e];
        atomicAdd(&ldeg[(p >> 17) & 255], 1);
    }
    __syncthreads();
    int n = b * 256 + tid;
    if (n < Nn) dinv[n] = rsqrtf((float)(ldeg[tid] + 1));  // +1 self loop
}

// ---------------- kernel: hs = (x @ W1) * dinv ; agg init = hs (round-8 form) ----------------
// block = 256 threads, 256 nodes/block; thread = (nodeq 0..63, hq 0..3)
__global__ __launch_bounds__(256) void k_gemm1(const void* __restrict__ xraw,
                                               const void* __restrict__ w1raw,
                                               const int* __restrict__ flags,
                                               const float* __restrict__ dinv,
                                               float* __restrict__ hs,
                                               float* __restrict__ agg, int Nn) {
    __shared__ float sWt[16 * 132];
    const int isbf = flags[0];
    const ushort* xb = (const ushort*)xraw;
    const float* xf = (const float*)xraw;
    int tid = threadIdx.x;
    if (isbf) {
        const ushort* w1 = (const ushort*)w1raw;
        for (int i = tid; i < 2048; i += 256) {
            int k = i >> 4, j = i & 15;
            sWt[j * 132 + k] = bf2f(w1[i]);
        }
    } else {
        const float* w1 = (const float*)w1raw;
        for (int i = tid; i < 2048; i += 256) {
            int k = i >> 4, j = i & 15;
            sWt[j * 132 + k] = w1[i];
        }
    }
    __syncthreads();
    int hq = tid & 3;
    int nodeq = tid >> 2;
    int n0 = blockIdx.x * 256 + nodeq * 4;
    float acc[4][4] = {};
    for (int ko = 0; ko < 16; ++ko) {
        float xv[4][8];
        #pragma unroll
        for (int r = 0; r < 4; ++r) {
            int n = n0 + r;
            if (n < Nn) {
                if (isbf) {
                    uint4 q = *reinterpret_cast<const uint4*>(xb + (size_t)n * 128 + ko * 8);
                    xv[r][0] = bf2f(q.x & 0xffffu); xv[r][1] = bf2f(q.x >> 16);
                    xv[r][2] = bf2f(q.y & 0xffffu); xv[r][3] = bf2f(q.y >> 16);
                    xv[r][4] = bf2f(q.z & 0xffffu); xv[r][5] = bf2f(q.z >> 16);
                    xv[r][6] = bf2f(q.w & 0xffffu); xv[r][7] = bf2f(q.w >> 16);
                } else {
                    const float4* p = reinterpret_cast<const float4*>(xf + (size_t)n * 128 + ko * 8);
                    float4 a = p[0], bb = p[1];
                    xv[r][0] = a.x; xv[r][1] = a.y; xv[r][2] = a.z; xv[r][3] = a.w;
                    xv[r][4] = bb.x; xv[r][5] = bb.y; xv[r][6] = bb.z; xv[r][7] = bb.w;
                }
            } else {
                #pragma unroll
                for (int u = 0; u < 8; ++u) xv[r][u] = 0.f;
            }
        }
        #pragma unroll
        for (int c = 0; c < 4; ++c) {
            const float* wr = &sWt[(hq * 4 + c) * 132 + ko * 8];
            float4 w0 = *reinterpret_cast<const float4*>(wr);
            float4 w1v = *reinterpret_cast<const float4*>(wr + 4);
            #pragma unroll
            for (int r = 0; r < 4; ++r) {
                acc[r][c] += xv[r][0] * w0.x + xv[r][1] * w0.y + xv[r][2] * w0.z + xv[r][3] * w0.w
                           + xv[r][4] * w1v.x + xv[r][5] * w1v.y + xv[r][6] * w1v.z + xv[r][7] * w1v.w;
            }
        }
    }
    #pragma unroll
    for (int r = 0; r < 4; ++r) {
        int n = n0 + r;
        if (n < Nn) {
            float dv = dinv[n];
            float4 o = make_float4(acc[r][0] * dv, acc[r][1] * dv, acc[r][2] * dv, acc[r][3] * dv);
            *reinterpret_cast<float4*>(hs + (size_t)n * 16 + hq * 4) = o;
            *reinterpret_cast<float4*>(agg + (size_t)n * 16 + hq * 4) = o;  // self-loop init
        }
    }
}

// ---------------- kernel: split bucket agg — register-staged counting-sort + runs ----------------
#define SPLITS 4
#define ACH 2048
__global__ __launch_bounds__(256) void k_aggS(const unsigned int* __restrict__ bkt,
                                              const int* __restrict__ base,
                                              const float* __restrict__ hs,
                                              float* __restrict__ agg, int Nn) {
    __shared__ float sAgg[4096];          // 16 KB
    __shared__ unsigned int sSorted[ACH]; // 8 KB
    __shared__ int cnt[256], excl[256];
    __shared__ int sc[2][256];
    __shared__ int tot_s;
    int tid = threadIdx.x;
    int b = blockIdx.x >> 2, sp = blockIdx.x & 3;
    for (int i = tid; i < 4096; i += 256) sAgg[i] = 0.f;
    int st = base[b], en = base[b + 1];
    int len = en - st;
    int s0 = st + (int)(((long long)len * sp) >> 2);
    int s1 = st + (int)(((long long)len * (sp + 1)) >> 2);
    int g = tid >> 4, j = tid & 15;
    for (int c0 = s0; c0 < s1; c0 += ACH) {
        cnt[tid] = 0;
        __syncthreads();
        // register-stage up to 8 entries/thread; histogram by node-in-bucket
        unsigned ue[8];
        #pragma unroll
        for (int i = 0; i < 8; ++i) {
            int idx = c0 + i * 256 + tid;
            if (idx < s1) {
                ue[i] = bkt[idx];
                atomicAdd(&cnt[(ue[i] >> 17) & 255u], 1);
            } else ue[i] = 0xffffffffu;
        }
        __syncthreads();
        // 256-wide scan of cnt
        int v = cnt[tid];
        sc[0][tid] = v;
        __syncthreads();
        int pi = 0;
        for (int off = 1; off < 256; off <<= 1) {
            sc[pi ^ 1][tid] = sc[pi][tid] + ((tid >= off) ? sc[pi][tid - off] : 0);
            __syncthreads();
            pi ^= 1;
        }
        int ex = sc[pi][tid] - v;
        excl[tid] = ex;
        cnt[tid] = ex;   // becomes running cursor
        if (tid == 255) tot_s = sc[pi][255];
        __syncthreads();
        // scatter from registers into sorted LDS order
        #pragma unroll
        for (int i = 0; i < 8; ++i) {
            if (ue[i] != 0xffffffffu) {
                int q = atomicAdd(&cnt[(ue[i] >> 17) & 255u], 1);
                sSorted[q] = ue[i];
            }
        }
        __syncthreads();
        // register-run accumulation: group g owns nodes [g*16, g*16+16)
        int segS = excl[g * 16];
        int segE = (g == 15) ? tot_s : excl[g * 16 + 16];
        float acc = 0.f; int curn = -1;
        for (int k = segS; k < segE; k += 8) {
            int m = segE - k;
            unsigned e[8]; float vv[8];
            #pragma unroll
            for (int i = 0; i < 8; ++i) e[i] = (i < m) ? sSorted[k + i] : 0xffffffffu;
            #pragma unroll
            for (int i = 0; i < 8; ++i)
                vv[i] = (e[i] != 0xffffffffu) ? hs[(size_t)(e[i] & 0x1ffffu) * 16 + j] : 0.f;
            #pragma unroll
            for (int i = 0; i < 8; ++i) {
                if (e[i] != 0xffffffffu) {
                    int nn = (int)((e[i] >> 17) & 255u);
                    if (nn != curn) { if (curn >= 0) sAgg[curn * 16 + j] += acc; acc = 0.f; curn = nn; }
                    acc += vv[i];
                }
            }
        }
        if (curn >= 0) sAgg[curn * 16 + j] += acc;
        __syncthreads();
    }
    // coalesced zero-skip combine into global agg
    int nbase = b << 8;
    for (int i = tid; i < 4096; i += 256) {
        int n = nbase + (i >> 4);
        float v = sAgg[i];
        bool nz = (n < Nn) && (v != 0.f);
        if (__any(nz)) {
            if (n < Nn) atomAddF(&agg[(size_t)n * 16 + (i & 15)], v);
        }
    }
}

// ---------------- kernel: *dinv + bias + relu -> @Wp+bp -> softmax -> out ----------------
__global__ __launch_bounds__(256) void k_final(const float* __restrict__ agg,
                                               const float* __restrict__ dinv,
                                               const void* __restrict__ b1raw,
                                               const void* __restrict__ wpraw,
                                               const void* __restrict__ bpraw,
                                               const int* __restrict__ flags,
                                               void* __restrict__ outraw, int Nn) {
    __shared__ float sWp[256];
    __shared__ float sA[256];
    const int isbf = flags[0];
    int tid = threadIdx.x;
    sWp[tid] = isbf ? bf2f(((const ushort*)wpraw)[tid]) : ((const float*)wpraw)[tid];
    int n0 = blockIdx.x * 16;
    int nl = tid >> 4, c = tid & 15;
    int n = n0 + nl;
    float b1v = isbf ? bf2f(((const ushort*)b1raw)[c]) : ((const float*)b1raw)[c];
    float bpv = isbf ? bf2f(((const ushort*)bpraw)[c]) : ((const float*)bpraw)[c];
    float av = (n < Nn) ? agg[(size_t)n * 16 + c] * dinv[n] : 0.f;
    sA[tid] = fmaxf(av + b1v, 0.f);
    __syncthreads();
    float acc = bpv;
    #pragma unroll
    for (int jj = 0; jj < 16; ++jj) acc += sA[nl * 16 + jj] * sWp[jj * 16 + c];
    float m = acc;
    #pragma unroll
    for (int off = 1; off < 16; off <<= 1) m = fmaxf(m, __shfl_xor(m, off, 16));
    float ev = __expf(acc - m);
    float s = ev;
    #pragma unroll
    for (int off = 1; off < 16; off <<= 1) s += __shfl_xor(s, off, 16);
    if (n < Nn) {
        float v = ev / s;
        if (isbf) ((ushort*)outraw)[(size_t)n * 16 + c] = f2bf(v);
        else      ((float*)outraw)[(size_t)n * 16 + c] = v;
    }
}

extern "C" void kernel_launch(void* const* d_in, const int* in_sizes, int n_in,
                              void* d_out, int out_size, void* d_ws, size_t ws_size,
                              hipStream_t stream) {
    const void* x  = d_in[0];
    const void* W1 = d_in[1];
    const void* b1 = d_in[2];
    const void* Wp = d_in[3];
    const void* bp = d_in[4];
    const int*  ei = (const int*)d_in[5];

    int Nn = in_sizes[0] / 128;
    int E  = in_sizes[5] / 2;
    int NB = (Nn + 255) >> 8;

    size_t Ns = (size_t)Nn;
    char* ws = (char*)d_ws;
    size_t off = 0;
    auto alloc = [&](size_t bytes) { void* p = ws + off; off += (bytes + 63) & ~(size_t)63; return p; };
    int*          flags  = (int*)alloc(64);
    float*        hs     = (float*)alloc(Ns * 16 * 4);
    float*        agg    = (float*)alloc(Ns * 16 * 4);
    float*        dinv   = (float*)alloc(Ns * 4);
    int*          hist   = (int*)alloc(512 * 4);
    int*          basep  = (int*)alloc(513 * 4);
    int*          cursor = (int*)alloc(512 * 4);
    unsigned int* bkt    = (unsigned int*)alloc((size_t)E * 4);

    k_detect<<<1, 256, 0, stream>>>((const unsigned int*)x, (const unsigned int*)ei, flags, hist);
    k_hist<<<(E + 2047) / 2048, 256, 0, stream>>>(ei, flags, hist, E, Nn);
    k_scanB<<<1, 512, 0, stream>>>(hist, basep, cursor, NB);
    k_part<<<(E + PCHUNK - 1) / PCHUNK, 256, 0, stream>>>(ei, flags, cursor, bkt, E, Nn);
    k_dinv<<<NB, 256, 0, stream>>>(bkt, basep, dinv, Nn);
    k_gemm1<<<(Nn + 255) / 256, 256, 0, stream>>>(x, W1, flags, dinv, hs, agg, Nn);
    k_aggS<<<NB * SPLITS, 256, 0, stream>>>(bkt, basep, hs, agg, Nn);
    k_final<<<(Nn + 15) / 16, 256, 0, stream>>>(agg, dinv, b1, Wp, bp, flags, d_out, Nn);
}